// Round 1
// baseline (12741.927 us; speedup 1.0000x reference)
//
#include <hip/hip_runtime.h>
#include <cmath>

#define NN 200000
#define EE 6400000

// ---------- float <-> order-preserving uint key ----------
__device__ __forceinline__ unsigned int f2key(float f) {
    unsigned int u = __float_as_uint(f);
    return (u & 0x80000000u) ? ~u : (u | 0x80000000u);
}
__device__ __forceinline__ float key2f(unsigned int k) {
    unsigned int u = (k & 0x80000000u) ? (k & 0x7FFFFFFFu) : ~k;
    return __uint_as_float(u);
}

// ---------- degree count over col ----------
__global__ void count_deg_kernel(const int* __restrict__ col, int* __restrict__ deg, int e) {
    int i = blockIdx.x * blockDim.x + threadIdx.x;
    if (i >= e) return;
    atomicAdd(&deg[col[i]], 1);
}

__global__ void dinv_kernel(const int* __restrict__ deg, float* __restrict__ dinv, int n) {
    int i = blockIdx.x * blockDim.x + threadIdx.x;
    if (i >= n) return;
    // +1 for the self loop
    dinv[i] = rsqrtf((float)(deg[i] + 1));
}

// ---------- dense matmul: out[i,:] = h[i,:] @ W  (W is [DIN,DOUT] row-major) ----------
template<int DIN, int DOUT>
__global__ void matmul_kernel(const float* __restrict__ h, const float* __restrict__ W,
                              float* __restrict__ out, int n) {
    __shared__ float Ws[DIN * DOUT];
    for (int t = threadIdx.x; t < DIN * DOUT; t += blockDim.x) Ws[t] = W[t];
    __syncthreads();
    int i = blockIdx.x * blockDim.x + threadIdx.x;
    if (i >= n) return;
    float acc[DOUT];
#pragma unroll
    for (int j = 0; j < DOUT; ++j) acc[j] = 0.f;
    const float* hr = h + (size_t)i * DIN;
#pragma unroll 4
    for (int k = 0; k < DIN; ++k) {
        float hv = hr[k];
#pragma unroll
        for (int j = 0; j < DOUT; ++j) acc[j] += hv * Ws[k * DOUT + j];
    }
    float* orow = out + (size_t)i * DOUT;
#pragma unroll
    for (int j = 0; j < DOUT; ++j) orow[j] = acc[j];
}

// ---------- init agg with the self-loop message: dinv[i]^2 * xl[i,:] ----------
template<int DOUT>
__global__ void self_init_kernel(const float* __restrict__ dinv, const float* __restrict__ xl,
                                 unsigned int* __restrict__ agg, int n) {
    int i = blockIdx.x * blockDim.x + threadIdx.x;
    if (i >= n) return;
    float d = dinv[i];
    float nrm = d * d;
    const float* xr = xl + (size_t)i * DOUT;
    unsigned int* ar = agg + (size_t)i * DOUT;
#pragma unroll
    for (int j = 0; j < DOUT; ++j) ar[j] = f2key(nrm * xr[j]);
}

// ---------- per-edge scatter max ----------
template<int DOUT>
__global__ void scatter_max_kernel(const int* __restrict__ row, const int* __restrict__ col,
                                   const float* __restrict__ dinv, const float* __restrict__ xl,
                                   unsigned int* __restrict__ agg, int e) {
    int idx = blockIdx.x * blockDim.x + threadIdx.x;
    if (idx >= e) return;
    int r = row[idx];
    int c = col[idx];
    float nrm = dinv[r] * dinv[c];
    const float* xr = xl + (size_t)r * DOUT;
    unsigned int* ar = agg + (size_t)c * DOUT;
#pragma unroll
    for (int j = 0; j < DOUT; ++j) {
        atomicMax(&ar[j], f2key(nrm * xr[j]));
    }
}

// ---------- decode agg keys, add bias, tanh ----------
template<int DOUT>
__global__ void tanh_bias_kernel(const unsigned int* __restrict__ agg, const float* __restrict__ b,
                                 float* __restrict__ h, int n) {
    int i = blockIdx.x * blockDim.x + threadIdx.x;
    if (i >= n) return;
    float bl[DOUT];
#pragma unroll
    for (int j = 0; j < DOUT; ++j) bl[j] = b[j];
    const unsigned int* ar = agg + (size_t)i * DOUT;
    float* hr = h + (size_t)i * DOUT;
#pragma unroll
    for (int j = 0; j < DOUT; ++j) hr[j] = tanhf(key2f(ar[j]) + bl[j]);
}

// ---------- classifier: out = h @ Wc + bc; also emit h ----------
__global__ void classifier_kernel(const float* __restrict__ h, const float* __restrict__ Wc,
                                  const float* __restrict__ bc, float* __restrict__ out,
                                  float* __restrict__ hout, int n) {
    int i = blockIdx.x * blockDim.x + threadIdx.x;
    if (i >= n) return;
    float h0 = h[(size_t)i * 2 + 0];
    float h1 = h[(size_t)i * 2 + 1];
#pragma unroll
    for (int c = 0; c < 4; ++c) {
        out[(size_t)i * 4 + c] = h0 * Wc[c] + h1 * Wc[4 + c] + bc[c];
    }
    hout[(size_t)i * 2 + 0] = h0;
    hout[(size_t)i * 2 + 1] = h1;
}

extern "C" void kernel_launch(void* const* d_in, const int* in_sizes, int n_in,
                              void* d_out, int out_size, void* d_ws, size_t ws_size,
                              hipStream_t stream) {
    const float* x  = (const float*)d_in[0];
    const int*   ei = (const int*)d_in[1];
    const int* row = ei;            // edge_index[0] = source
    const int* col = ei + EE;       // edge_index[1] = target
    const float* W1 = (const float*)d_in[2];  const float* b1 = (const float*)d_in[3];
    const float* W2 = (const float*)d_in[4];  const float* b2 = (const float*)d_in[5];
    const float* W3 = (const float*)d_in[6];  const float* b3 = (const float*)d_in[7];
    const float* W4 = (const float*)d_in[8];  const float* b4 = (const float*)d_in[9];
    const float* W5 = (const float*)d_in[10]; const float* b5 = (const float*)d_in[11];
    const float* Wc = (const float*)d_in[12]; const float* bc = (const float*)d_in[13];
    float* out = (float*)d_out;

    // workspace carve (all offsets multiple of 256B)
    char* ws = (char*)d_ws;
    int*          deg  = (int*)ws;                                   // N ints    = 800000 B
    float*        dinv = (float*)(ws + 800000);                      // N floats  = 800000 B
    float*        bufA = (float*)(ws + 1600000);                     // N*24 f    = 19.2 MB (h)
    float*        bufB = (float*)(ws + 1600000 + 19200000);          // N*24 f    = 19.2 MB (xl)
    unsigned int* bufC = (unsigned int*)(ws + 1600000 + 38400000);   // N*24 u    = 19.2 MB (agg keys)

    const int BLK = 256;
    const int gN = (NN + BLK - 1) / BLK;
    const int gE = (EE + BLK - 1) / BLK;

    hipMemsetAsync(deg, 0, NN * sizeof(int), stream);
    count_deg_kernel<<<gE, BLK, 0, stream>>>(col, deg, EE);
    dinv_kernel<<<gN, BLK, 0, stream>>>(deg, dinv, NN);

    // Layer 1: 128 -> 24
    matmul_kernel<128, 24><<<gN, BLK, 0, stream>>>(x, W1, bufB, NN);
    self_init_kernel<24><<<gN, BLK, 0, stream>>>(dinv, bufB, bufC, NN);
    scatter_max_kernel<24><<<gE, BLK, 0, stream>>>(row, col, dinv, bufB, bufC, EE);
    tanh_bias_kernel<24><<<gN, BLK, 0, stream>>>(bufC, b1, bufA, NN);

    // Layer 2: 24 -> 12
    matmul_kernel<24, 12><<<gN, BLK, 0, stream>>>(bufA, W2, bufB, NN);
    self_init_kernel<12><<<gN, BLK, 0, stream>>>(dinv, bufB, bufC, NN);
    scatter_max_kernel<12><<<gE, BLK, 0, stream>>>(row, col, dinv, bufB, bufC, EE);
    tanh_bias_kernel<12><<<gN, BLK, 0, stream>>>(bufC, b2, bufA, NN);

    // Layer 3: 12 -> 6
    matmul_kernel<12, 6><<<gN, BLK, 0, stream>>>(bufA, W3, bufB, NN);
    self_init_kernel<6><<<gN, BLK, 0, stream>>>(dinv, bufB, bufC, NN);
    scatter_max_kernel<6><<<gE, BLK, 0, stream>>>(row, col, dinv, bufB, bufC, EE);
    tanh_bias_kernel<6><<<gN, BLK, 0, stream>>>(bufC, b3, bufA, NN);

    // Layer 4: 6 -> 4
    matmul_kernel<6, 4><<<gN, BLK, 0, stream>>>(bufA, W4, bufB, NN);
    self_init_kernel<4><<<gN, BLK, 0, stream>>>(dinv, bufB, bufC, NN);
    scatter_max_kernel<4><<<gE, BLK, 0, stream>>>(row, col, dinv, bufB, bufC, EE);
    tanh_bias_kernel<4><<<gN, BLK, 0, stream>>>(bufC, b4, bufA, NN);

    // Layer 5: 4 -> 2
    matmul_kernel<4, 2><<<gN, BLK, 0, stream>>>(bufA, W5, bufB, NN);
    self_init_kernel<2><<<gN, BLK, 0, stream>>>(dinv, bufB, bufC, NN);
    scatter_max_kernel<2><<<gE, BLK, 0, stream>>>(row, col, dinv, bufB, bufC, EE);
    tanh_bias_kernel<2><<<gN, BLK, 0, stream>>>(bufC, b5, bufA, NN);

    // Classifier: 2 -> 4, plus emit h
    classifier_kernel<<<gN, BLK, 0, stream>>>(bufA, Wc, bc, out, out + (size_t)NN * 4, NN);
}

// Round 2
// 1660.631 us; speedup vs baseline: 7.6729x; 7.6729x over previous
//
#include <hip/hip_runtime.h>
#include <cmath>

#define NN 200000
#define EE 6400000

// =============== CSR build ===============

__global__ void count_deg_kernel(const int* __restrict__ col, int* __restrict__ deg, int e) {
    int i = blockIdx.x * blockDim.x + threadIdx.x;
    if (i >= e) return;
    atomicAdd(&deg[col[i]], 1);
}

__global__ void dinv_kernel(const int* __restrict__ deg, float* __restrict__ dinv, int n) {
    int i = blockIdx.x * blockDim.x + threadIdx.x;
    if (i >= n) return;
    dinv[i] = rsqrtf((float)(deg[i] + 1));   // +1 self loop
}

// per-block exclusive scan of deg -> offs, block sums -> bsum
__global__ void scan_block_kernel(const int* __restrict__ deg, int* __restrict__ offs,
                                  int* __restrict__ bsum, int n) {
    __shared__ int tmp[256];
    int i = blockIdx.x * 256 + threadIdx.x;
    int v = (i < n) ? deg[i] : 0;
    tmp[threadIdx.x] = v;
    __syncthreads();
    for (int off = 1; off < 256; off <<= 1) {
        int add = (threadIdx.x >= off) ? tmp[threadIdx.x - off] : 0;
        __syncthreads();
        tmp[threadIdx.x] += add;
        __syncthreads();
    }
    if (i < n) offs[i] = tmp[threadIdx.x] - v;           // exclusive within block
    if (threadIdx.x == 255) bsum[blockIdx.x] = tmp[255]; // block total
}

// single-block exclusive scan of block sums (nb <= 1024)
__global__ void scan_bsum_kernel(int* __restrict__ bsum, int nb) {
    __shared__ int tmp[1024];
    int t = threadIdx.x;
    int v = (t < nb) ? bsum[t] : 0;
    tmp[t] = v;
    __syncthreads();
    for (int off = 1; off < 1024; off <<= 1) {
        int add = (t >= off) ? tmp[t - off] : 0;
        __syncthreads();
        tmp[t] += add;
        __syncthreads();
    }
    if (t < nb) bsum[t] = tmp[t] - v;  // exclusive
}

__global__ void add_offsets_kernel(int* __restrict__ offs, const int* __restrict__ bsum,
                                   int* __restrict__ cursor, int n) {
    int i = blockIdx.x * 256 + threadIdx.x;
    if (i >= n) return;
    int o = offs[i] + bsum[blockIdx.x];
    offs[i] = o;
    cursor[i] = o;
}

__global__ void place_kernel(const int* __restrict__ row, const int* __restrict__ col,
                             int* __restrict__ cursor, int* __restrict__ row_sorted, int e) {
    int i = blockIdx.x * blockDim.x + threadIdx.x;
    if (i >= e) return;
    int c = col[i];
    int p = atomicAdd(&cursor[c], 1);
    row_sorted[p] = row[i];
}

// =============== dense matmuls ===============

// layer 1: DIN=128, float4 loads
template<int DOUT>
__global__ void matmul128_kernel(const float* __restrict__ h, const float* __restrict__ W,
                                 float* __restrict__ out, int n) {
    __shared__ float Ws[128 * DOUT];
    for (int t = threadIdx.x; t < 128 * DOUT; t += blockDim.x) Ws[t] = W[t];
    __syncthreads();
    int i = blockIdx.x * blockDim.x + threadIdx.x;
    if (i >= n) return;
    float acc[DOUT];
#pragma unroll
    for (int j = 0; j < DOUT; ++j) acc[j] = 0.f;
    const float4* hr = (const float4*)(h + (size_t)i * 128);
#pragma unroll 8
    for (int k4 = 0; k4 < 32; ++k4) {
        float4 hv = hr[k4];
        const float* wk = &Ws[k4 * 4 * DOUT];
#pragma unroll
        for (int j = 0; j < DOUT; ++j) acc[j] += hv.x * wk[j];
#pragma unroll
        for (int j = 0; j < DOUT; ++j) acc[j] += hv.y * wk[DOUT + j];
#pragma unroll
        for (int j = 0; j < DOUT; ++j) acc[j] += hv.z * wk[2 * DOUT + j];
#pragma unroll
        for (int j = 0; j < DOUT; ++j) acc[j] += hv.w * wk[3 * DOUT + j];
    }
    float* orow = out + (size_t)i * DOUT;
#pragma unroll
    for (int j = 0; j < DOUT; ++j) orow[j] = acc[j];
}

// small inner layers
template<int DIN, int DOUT>
__global__ void matmul_kernel(const float* __restrict__ h, const float* __restrict__ W,
                              float* __restrict__ out, int n) {
    __shared__ float Ws[DIN * DOUT];
    for (int t = threadIdx.x; t < DIN * DOUT; t += blockDim.x) Ws[t] = W[t];
    __syncthreads();
    int i = blockIdx.x * blockDim.x + threadIdx.x;
    if (i >= n) return;
    float acc[DOUT];
#pragma unroll
    for (int j = 0; j < DOUT; ++j) acc[j] = 0.f;
    const float* hr = h + (size_t)i * DIN;
#pragma unroll
    for (int k = 0; k < DIN; ++k) {
        float hv = hr[k];
#pragma unroll
        for (int j = 0; j < DOUT; ++j) acc[j] += hv * Ws[k * DOUT + j];
    }
    float* orow = out + (size_t)i * DOUT;
#pragma unroll
    for (int j = 0; j < DOUT; ++j) orow[j] = acc[j];
}

// =============== gather max + bias + tanh ===============
// thread t -> (node = t/DOUT, feature j = t%DOUT); coalesced xl gathers within group
template<int DOUT>
__global__ void gather_max_tanh_kernel(const int* __restrict__ offs, const int* __restrict__ deg,
                                       const int* __restrict__ row_sorted,
                                       const float* __restrict__ dinv,
                                       const float* __restrict__ xl,
                                       const float* __restrict__ b,
                                       float* __restrict__ h, int n) {
    int t = blockIdx.x * blockDim.x + threadIdx.x;
    int node = t / DOUT;
    int j = t - node * DOUT;
    if (node >= n) return;
    float dc = dinv[node];
    // self loop message seeds the max
    float m = dc * dc * xl[(size_t)node * DOUT + j];
    int s = offs[node];
    int e = s + deg[node];
    for (int k = s; k < e; ++k) {
        int r = row_sorted[k];
        float nrm = dinv[r] * dc;
        m = fmaxf(m, nrm * xl[(size_t)r * DOUT + j]);
    }
    h[(size_t)node * DOUT + j] = tanhf(m + b[j]);
}

// =============== classifier ===============
__global__ void classifier_kernel(const float* __restrict__ h, const float* __restrict__ Wc,
                                  const float* __restrict__ bc, float* __restrict__ out,
                                  float* __restrict__ hout, int n) {
    int i = blockIdx.x * blockDim.x + threadIdx.x;
    if (i >= n) return;
    float h0 = h[(size_t)i * 2 + 0];
    float h1 = h[(size_t)i * 2 + 1];
#pragma unroll
    for (int c = 0; c < 4; ++c) {
        out[(size_t)i * 4 + c] = h0 * Wc[c] + h1 * Wc[4 + c] + bc[c];
    }
    hout[(size_t)i * 2 + 0] = h0;
    hout[(size_t)i * 2 + 1] = h1;
}

extern "C" void kernel_launch(void* const* d_in, const int* in_sizes, int n_in,
                              void* d_out, int out_size, void* d_ws, size_t ws_size,
                              hipStream_t stream) {
    const float* x  = (const float*)d_in[0];
    const int*   ei = (const int*)d_in[1];
    const int* row = ei;            // edge_index[0] = source
    const int* col = ei + EE;       // edge_index[1] = target
    const float* W1 = (const float*)d_in[2];  const float* b1 = (const float*)d_in[3];
    const float* W2 = (const float*)d_in[4];  const float* b2 = (const float*)d_in[5];
    const float* W3 = (const float*)d_in[6];  const float* b3 = (const float*)d_in[7];
    const float* W4 = (const float*)d_in[8];  const float* b4 = (const float*)d_in[9];
    const float* W5 = (const float*)d_in[10]; const float* b5 = (const float*)d_in[11];
    const float* Wc = (const float*)d_in[12]; const float* bc = (const float*)d_in[13];
    float* out = (float*)d_out;

    // workspace carve (16B-aligned offsets)
    char* ws = (char*)d_ws;
    int*   deg        = (int*)(ws + 0);            // 800,000 B
    float* dinv       = (float*)(ws + 800000);     // 800,000 B
    int*   offs       = (int*)(ws + 1600000);      // 800,000 B
    int*   cursor     = (int*)(ws + 2400000);      // 800,000 B
    int*   bsum       = (int*)(ws + 3200000);      // 4,096 B
    int*   row_sorted = (int*)(ws + 4000000);      // 25,600,000 B
    float* bufA       = (float*)(ws + 29600000);   // 19,200,000 B (h)
    float* bufB       = (float*)(ws + 48800000);   // 19,200,000 B (xl)

    const int BLK = 256;
    const int gN = (NN + BLK - 1) / BLK;       // 782
    const int gE = (EE + BLK - 1) / BLK;

    // ---- CSR build ----
    hipMemsetAsync(deg, 0, NN * sizeof(int), stream);
    count_deg_kernel<<<gE, BLK, 0, stream>>>(col, deg, EE);
    dinv_kernel<<<gN, BLK, 0, stream>>>(deg, dinv, NN);
    scan_block_kernel<<<gN, BLK, 0, stream>>>(deg, offs, bsum, NN);
    scan_bsum_kernel<<<1, 1024, 0, stream>>>(bsum, gN);
    add_offsets_kernel<<<gN, BLK, 0, stream>>>(offs, bsum, cursor, NN);
    place_kernel<<<gE, BLK, 0, stream>>>(row, col, cursor, row_sorted, EE);

    // ---- layer 1: 128 -> 24 ----
    matmul128_kernel<24><<<gN, BLK, 0, stream>>>(x, W1, bufB, NN);
    {
        int total = NN * 24;
        gather_max_tanh_kernel<24><<<(total + BLK - 1) / BLK, BLK, 0, stream>>>(
            offs, deg, row_sorted, dinv, bufB, b1, bufA, NN);
    }
    // ---- layer 2: 24 -> 12 ----
    matmul_kernel<24, 12><<<gN, BLK, 0, stream>>>(bufA, W2, bufB, NN);
    {
        int total = NN * 12;
        gather_max_tanh_kernel<12><<<(total + BLK - 1) / BLK, BLK, 0, stream>>>(
            offs, deg, row_sorted, dinv, bufB, b2, bufA, NN);
    }
    // ---- layer 3: 12 -> 6 ----
    matmul_kernel<12, 6><<<gN, BLK, 0, stream>>>(bufA, W3, bufB, NN);
    {
        int total = NN * 6;
        gather_max_tanh_kernel<6><<<(total + BLK - 1) / BLK, BLK, 0, stream>>>(
            offs, deg, row_sorted, dinv, bufB, b3, bufA, NN);
    }
    // ---- layer 4: 6 -> 4 ----
    matmul_kernel<6, 4><<<gN, BLK, 0, stream>>>(bufA, W4, bufB, NN);
    {
        int total = NN * 4;
        gather_max_tanh_kernel<4><<<(total + BLK - 1) / BLK, BLK, 0, stream>>>(
            offs, deg, row_sorted, dinv, bufB, b4, bufA, NN);
    }
    // ---- layer 5: 4 -> 2 ----
    matmul_kernel<4, 2><<<gN, BLK, 0, stream>>>(bufA, W5, bufB, NN);
    {
        int total = NN * 2;
        gather_max_tanh_kernel<2><<<(total + BLK - 1) / BLK, BLK, 0, stream>>>(
            offs, deg, row_sorted, dinv, bufB, b5, bufA, NN);
    }

    // ---- classifier: 2 -> 4, plus emit h ----
    classifier_kernel<<<gN, BLK, 0, stream>>>(bufA, Wc, bc, out, out + (size_t)NN * 4, NN);
}

// Round 3
// 1025.543 us; speedup vs baseline: 12.4246x; 1.6193x over previous
//
#include <hip/hip_runtime.h>
#include <cmath>

#define NN 200000
#define EE 6400000
#define NBKT 391          // ceil(200000 / 512), bucket = col >> 9
#define GRID_A 512        // blocks in phase-A kernels (MUST match scan width)
#define BLK_A 256

// =============== Phase A: bucket edges by col>>9 (counting sort, LDS atomics only) ===============

// A1: per-block LDS histogram of buckets -> blkhist[block][bucket]
__global__ __launch_bounds__(BLK_A) void count_buckets_kernel(const int* __restrict__ col,
                                                              int* __restrict__ blkhist) {
    __shared__ int h[NBKT];
    for (int t = threadIdx.x; t < NBKT; t += BLK_A) h[t] = 0;
    __syncthreads();
    for (int i = blockIdx.x * BLK_A + threadIdx.x; i < EE; i += GRID_A * BLK_A) {
        atomicAdd(&h[col[i] >> 9], 1);
    }
    __syncthreads();
    for (int t = threadIdx.x; t < NBKT; t += BLK_A) blkhist[blockIdx.x * NBKT + t] = h[t];
}

// A2a: per-bucket exclusive scan down the block axis (in place); bucket totals out.
// gridDim = NBKT, blockDim = GRID_A (=512)
__global__ __launch_bounds__(GRID_A) void scan_cols_kernel(int* __restrict__ blkhist,
                                                           int* __restrict__ btot) {
    __shared__ int sc[GRID_A];
    int bkt = blockIdx.x, t = threadIdx.x;
    int v = blkhist[t * NBKT + bkt];
    sc[t] = v;
    __syncthreads();
    for (int off = 1; off < GRID_A; off <<= 1) {
        int add = (t >= off) ? sc[t - off] : 0;
        __syncthreads();
        sc[t] += add;
        __syncthreads();
    }
    blkhist[t * NBKT + bkt] = sc[t] - v;  // exclusive along blocks
    if (t == GRID_A - 1) btot[bkt] = sc[t];
}

// A2b: exclusive scan of 391 bucket totals -> bucket_base[0..NBKT]
__global__ __launch_bounds__(512) void scan_btot_kernel(const int* __restrict__ btot,
                                                        int* __restrict__ bbase) {
    __shared__ int sc[512];
    int t = threadIdx.x;
    int v = (t < NBKT) ? btot[t] : 0;
    sc[t] = v;
    __syncthreads();
    for (int off = 1; off < 512; off <<= 1) {
        int add = (t >= off) ? sc[t - off] : 0;
        __syncthreads();
        sc[t] += add;
        __syncthreads();
    }
    if (t < NBKT) bbase[t] = sc[t] - v;
    if (t == NBKT - 1) bbase[NBKT] = sc[t];  // total = EE
}

// A3: place packed codes into bucket-grouped order. Same grid config / edge mapping as A1.
// code = (col & 511) << 18 | row   (row < 2^18)
__global__ __launch_bounds__(BLK_A) void place_pairs_kernel(const int* __restrict__ row,
                                                            const int* __restrict__ col,
                                                            const int* __restrict__ blkhist,
                                                            const int* __restrict__ bbase,
                                                            unsigned int* __restrict__ pairs) {
    __shared__ int cur[NBKT];
    for (int t = threadIdx.x; t < NBKT; t += BLK_A)
        cur[t] = bbase[t] + blkhist[blockIdx.x * NBKT + t];
    __syncthreads();
    for (int i = blockIdx.x * BLK_A + threadIdx.x; i < EE; i += GRID_A * BLK_A) {
        int c = col[i];
        int p = atomicAdd(&cur[c >> 9], 1);
        pairs[p] = (unsigned int)row[i] | ((unsigned int)(c & 511) << 18);
    }
}

// =============== Phase B: within each bucket, build CSR (deg/offs/dinv/row_sorted) ===============
// gridDim = NBKT, blockDim = 512
__global__ __launch_bounds__(512) void bucket_build_kernel(const unsigned int* __restrict__ pairs,
                                                           const int* __restrict__ bbase,
                                                           int* __restrict__ deg,
                                                           int* __restrict__ offs,
                                                           float* __restrict__ dinv,
                                                           int* __restrict__ row_sorted) {
    __shared__ int h[512];
    __shared__ int sc[512];
    int b = blockIdx.x, tid = threadIdx.x;
    int base = bbase[b], end = bbase[b + 1];
    int node0 = b << 9;
    int nloc = NN - node0; if (nloc > 512) nloc = 512;

    h[tid] = 0;
    __syncthreads();
    for (int i = base + tid; i < end; i += 512) atomicAdd(&h[pairs[i] >> 18], 1);
    __syncthreads();

    int v = h[tid];
    sc[tid] = v;
    __syncthreads();
    for (int off = 1; off < 512; off <<= 1) {
        int add = (tid >= off) ? sc[tid - off] : 0;
        __syncthreads();
        sc[tid] += add;
        __syncthreads();
    }
    int excl = sc[tid] - v;

    if (tid < nloc) {
        deg[node0 + tid]  = v;
        offs[node0 + tid] = base + excl;
        dinv[node0 + tid] = rsqrtf((float)(v + 1));  // +1 self loop
    }
    __syncthreads();
    h[tid] = base + excl;  // local cursor
    __syncthreads();
    for (int i = base + tid; i < end; i += 512) {
        unsigned int p = pairs[i];
        int pos = atomicAdd(&h[p >> 18], 1);
        row_sorted[pos] = (int)(p & 0x3FFFFu);
    }
}

// =============== dense matmuls ===============

template<int DOUT>
__global__ void matmul128_kernel(const float* __restrict__ h, const float* __restrict__ W,
                                 float* __restrict__ out, int n) {
    __shared__ float Ws[128 * DOUT];
    for (int t = threadIdx.x; t < 128 * DOUT; t += blockDim.x) Ws[t] = W[t];
    __syncthreads();
    int i = blockIdx.x * blockDim.x + threadIdx.x;
    if (i >= n) return;
    float acc[DOUT];
#pragma unroll
    for (int j = 0; j < DOUT; ++j) acc[j] = 0.f;
    const float4* hr = (const float4*)(h + (size_t)i * 128);
#pragma unroll 8
    for (int k4 = 0; k4 < 32; ++k4) {
        float4 hv = hr[k4];
        const float* wk = &Ws[k4 * 4 * DOUT];
#pragma unroll
        for (int j = 0; j < DOUT; ++j) acc[j] += hv.x * wk[j];
#pragma unroll
        for (int j = 0; j < DOUT; ++j) acc[j] += hv.y * wk[DOUT + j];
#pragma unroll
        for (int j = 0; j < DOUT; ++j) acc[j] += hv.z * wk[2 * DOUT + j];
#pragma unroll
        for (int j = 0; j < DOUT; ++j) acc[j] += hv.w * wk[3 * DOUT + j];
    }
    float* orow = out + (size_t)i * DOUT;
#pragma unroll
    for (int j = 0; j < DOUT; ++j) orow[j] = acc[j];
}

template<int DIN, int DOUT>
__global__ void matmul_kernel(const float* __restrict__ h, const float* __restrict__ W,
                              float* __restrict__ out, int n) {
    __shared__ float Ws[DIN * DOUT];
    for (int t = threadIdx.x; t < DIN * DOUT; t += blockDim.x) Ws[t] = W[t];
    __syncthreads();
    int i = blockIdx.x * blockDim.x + threadIdx.x;
    if (i >= n) return;
    float acc[DOUT];
#pragma unroll
    for (int j = 0; j < DOUT; ++j) acc[j] = 0.f;
    const float* hr = h + (size_t)i * DIN;
#pragma unroll
    for (int k = 0; k < DIN; ++k) {
        float hv = hr[k];
#pragma unroll
        for (int j = 0; j < DOUT; ++j) acc[j] += hv * Ws[k * DOUT + j];
    }
    float* orow = out + (size_t)i * DOUT;
#pragma unroll
    for (int j = 0; j < DOUT; ++j) orow[j] = acc[j];
}

// =============== gather max + bias + tanh ===============
template<int DOUT>
__global__ void gather_max_tanh_kernel(const int* __restrict__ offs, const int* __restrict__ deg,
                                       const int* __restrict__ row_sorted,
                                       const float* __restrict__ dinv,
                                       const float* __restrict__ xl,
                                       const float* __restrict__ b,
                                       float* __restrict__ h, int n) {
    int t = blockIdx.x * blockDim.x + threadIdx.x;
    int node = t / DOUT;
    int j = t - node * DOUT;
    if (node >= n) return;
    float dc = dinv[node];
    float m = dc * dc * xl[(size_t)node * DOUT + j];  // self loop seeds the max
    int s = offs[node];
    int e = s + deg[node];
    for (int k = s; k < e; ++k) {
        int r = row_sorted[k];
        float nrm = dinv[r] * dc;
        m = fmaxf(m, nrm * xl[(size_t)r * DOUT + j]);
    }
    h[(size_t)node * DOUT + j] = tanhf(m + b[j]);
}

// =============== classifier ===============
__global__ void classifier_kernel(const float* __restrict__ h, const float* __restrict__ Wc,
                                  const float* __restrict__ bc, float* __restrict__ out,
                                  float* __restrict__ hout, int n) {
    int i = blockIdx.x * blockDim.x + threadIdx.x;
    if (i >= n) return;
    float h0 = h[(size_t)i * 2 + 0];
    float h1 = h[(size_t)i * 2 + 1];
#pragma unroll
    for (int c = 0; c < 4; ++c) {
        out[(size_t)i * 4 + c] = h0 * Wc[c] + h1 * Wc[4 + c] + bc[c];
    }
    hout[(size_t)i * 2 + 0] = h0;
    hout[(size_t)i * 2 + 1] = h1;
}

extern "C" void kernel_launch(void* const* d_in, const int* in_sizes, int n_in,
                              void* d_out, int out_size, void* d_ws, size_t ws_size,
                              hipStream_t stream) {
    const float* x  = (const float*)d_in[0];
    const int*   ei = (const int*)d_in[1];
    const int* row = ei;            // edge_index[0] = source
    const int* col = ei + EE;       // edge_index[1] = target
    const float* W1 = (const float*)d_in[2];  const float* b1 = (const float*)d_in[3];
    const float* W2 = (const float*)d_in[4];  const float* b2 = (const float*)d_in[5];
    const float* W3 = (const float*)d_in[6];  const float* b3 = (const float*)d_in[7];
    const float* W4 = (const float*)d_in[8];  const float* b4 = (const float*)d_in[9];
    const float* W5 = (const float*)d_in[10]; const float* b5 = (const float*)d_in[11];
    const float* Wc = (const float*)d_in[12]; const float* bc = (const float*)d_in[13];
    float* out = (float*)d_out;

    // ---- workspace carve (offsets multiples of 256B) ----
    // pairs is dead before the first matmul writes bufB -> alias them.
    char* ws = (char*)d_ws;
    int*          deg        = (int*)(ws + 0);          //    800,000
    float*        dinv       = (float*)(ws + 800000);   //    800,000
    int*          offs       = (int*)(ws + 1600000);    //    800,000
    int*          bbase      = (int*)(ws + 2400000);    //      2,048  (NBKT+1 ints)
    int*          blkhist    = (int*)(ws + 2402048);    //    802,816  (GRID_A*NBKT ints)
    int*          btot       = (int*)(ws + 3204864);    //      2,048  (NBKT ints)
    unsigned int* pairs      = (unsigned int*)(ws + 3206912);   // 25,600,000
    float*        bufB       = (float*)(ws + 3206912);          // 19,200,000 (aliases pairs)
    int*          row_sorted = (int*)(ws + 28806912);           // 25,600,000
    float*        bufA       = (float*)(ws + 54406912);         // 19,200,000
    // total: 73,606,912 B

    const int BLK = 256;
    const int gN = (NN + BLK - 1) / BLK;       // 782

    // ---- CSR build: two-level counting sort, LDS atomics only ----
    count_buckets_kernel<<<GRID_A, BLK_A, 0, stream>>>(col, blkhist);
    scan_cols_kernel<<<NBKT, GRID_A, 0, stream>>>(blkhist, btot);
    scan_btot_kernel<<<1, 512, 0, stream>>>(btot, bbase);
    place_pairs_kernel<<<GRID_A, BLK_A, 0, stream>>>(row, col, blkhist, bbase, pairs);
    bucket_build_kernel<<<NBKT, 512, 0, stream>>>(pairs, bbase, deg, offs, dinv, row_sorted);

    // ---- layer 1: 128 -> 24 ----
    matmul128_kernel<24><<<gN, BLK, 0, stream>>>(x, W1, bufB, NN);
    gather_max_tanh_kernel<24><<<(NN * 24 + BLK - 1) / BLK, BLK, 0, stream>>>(
        offs, deg, row_sorted, dinv, bufB, b1, bufA, NN);

    // ---- layer 2: 24 -> 12 ----
    matmul_kernel<24, 12><<<gN, BLK, 0, stream>>>(bufA, W2, bufB, NN);
    gather_max_tanh_kernel<12><<<(NN * 12 + BLK - 1) / BLK, BLK, 0, stream>>>(
        offs, deg, row_sorted, dinv, bufB, b2, bufA, NN);

    // ---- layer 3: 12 -> 6 ----
    matmul_kernel<12, 6><<<gN, BLK, 0, stream>>>(bufA, W3, bufB, NN);
    gather_max_tanh_kernel<6><<<(NN * 6 + BLK - 1) / BLK, BLK, 0, stream>>>(
        offs, deg, row_sorted, dinv, bufB, b3, bufA, NN);

    // ---- layer 4: 6 -> 4 ----
    matmul_kernel<6, 4><<<gN, BLK, 0, stream>>>(bufA, W4, bufB, NN);
    gather_max_tanh_kernel<4><<<(NN * 4 + BLK - 1) / BLK, BLK, 0, stream>>>(
        offs, deg, row_sorted, dinv, bufB, b4, bufA, NN);

    // ---- layer 5: 4 -> 2 ----
    matmul_kernel<4, 2><<<gN, BLK, 0, stream>>>(bufA, W5, bufB, NN);
    gather_max_tanh_kernel<2><<<(NN * 2 + BLK - 1) / BLK, BLK, 0, stream>>>(
        offs, deg, row_sorted, dinv, bufB, b5, bufA, NN);

    // ---- classifier: 2 -> 4, plus emit h ----
    classifier_kernel<<<gN, BLK, 0, stream>>>(bufA, Wc, bc, out, out + (size_t)NN * 4, NN);
}

// Round 4
// 981.429 us; speedup vs baseline: 12.9830x; 1.0449x over previous
//
#include <hip/hip_runtime.h>
#include <cmath>

#define NN 200000
#define EE 6400000
#define NBKT 391          // ceil(200000 / 512), bucket = col >> 9
#define GRID_A 512        // blocks in phase-A kernels (MUST match scan width)
#define BLK_A 256

// =============== Phase A: bucket edges by col>>9 (counting sort, LDS atomics only) ===============

__global__ __launch_bounds__(BLK_A) void count_buckets_kernel(const int* __restrict__ col,
                                                              int* __restrict__ blkhist) {
    __shared__ int h[NBKT];
    for (int t = threadIdx.x; t < NBKT; t += BLK_A) h[t] = 0;
    __syncthreads();
    for (int i = blockIdx.x * BLK_A + threadIdx.x; i < EE; i += GRID_A * BLK_A) {
        atomicAdd(&h[col[i] >> 9], 1);
    }
    __syncthreads();
    for (int t = threadIdx.x; t < NBKT; t += BLK_A) blkhist[blockIdx.x * NBKT + t] = h[t];
}

__global__ __launch_bounds__(GRID_A) void scan_cols_kernel(int* __restrict__ blkhist,
                                                           int* __restrict__ btot) {
    __shared__ int sc[GRID_A];
    int bkt = blockIdx.x, t = threadIdx.x;
    int v = blkhist[t * NBKT + bkt];
    sc[t] = v;
    __syncthreads();
    for (int off = 1; off < GRID_A; off <<= 1) {
        int add = (t >= off) ? sc[t - off] : 0;
        __syncthreads();
        sc[t] += add;
        __syncthreads();
    }
    blkhist[t * NBKT + bkt] = sc[t] - v;  // exclusive along blocks
    if (t == GRID_A - 1) btot[bkt] = sc[t];
}

__global__ __launch_bounds__(512) void scan_btot_kernel(const int* __restrict__ btot,
                                                        int* __restrict__ bbase) {
    __shared__ int sc[512];
    int t = threadIdx.x;
    int v = (t < NBKT) ? btot[t] : 0;
    sc[t] = v;
    __syncthreads();
    for (int off = 1; off < 512; off <<= 1) {
        int add = (t >= off) ? sc[t - off] : 0;
        __syncthreads();
        sc[t] += add;
        __syncthreads();
    }
    if (t < NBKT) bbase[t] = sc[t] - v;
    if (t == NBKT - 1) bbase[NBKT] = sc[t];  // total = EE
}

__global__ __launch_bounds__(BLK_A) void place_pairs_kernel(const int* __restrict__ row,
                                                            const int* __restrict__ col,
                                                            const int* __restrict__ blkhist,
                                                            const int* __restrict__ bbase,
                                                            unsigned int* __restrict__ pairs) {
    __shared__ int cur[NBKT];
    for (int t = threadIdx.x; t < NBKT; t += BLK_A)
        cur[t] = bbase[t] + blkhist[blockIdx.x * NBKT + t];
    __syncthreads();
    for (int i = blockIdx.x * BLK_A + threadIdx.x; i < EE; i += GRID_A * BLK_A) {
        int c = col[i];
        int p = atomicAdd(&cur[c >> 9], 1);
        pairs[p] = (unsigned int)row[i] | ((unsigned int)(c & 511) << 18);
    }
}

__global__ __launch_bounds__(512) void bucket_build_kernel(const unsigned int* __restrict__ pairs,
                                                           const int* __restrict__ bbase,
                                                           int* __restrict__ deg,
                                                           int* __restrict__ offs,
                                                           float* __restrict__ dinv,
                                                           int* __restrict__ row_sorted) {
    __shared__ int h[512];
    __shared__ int sc[512];
    int b = blockIdx.x, tid = threadIdx.x;
    int base = bbase[b], end = bbase[b + 1];
    int node0 = b << 9;
    int nloc = NN - node0; if (nloc > 512) nloc = 512;

    h[tid] = 0;
    __syncthreads();
    for (int i = base + tid; i < end; i += 512) atomicAdd(&h[pairs[i] >> 18], 1);
    __syncthreads();

    int v = h[tid];
    sc[tid] = v;
    __syncthreads();
    for (int off = 1; off < 512; off <<= 1) {
        int add = (tid >= off) ? sc[tid - off] : 0;
        __syncthreads();
        sc[tid] += add;
        __syncthreads();
    }
    int excl = sc[tid] - v;

    if (tid < nloc) {
        deg[node0 + tid]  = v;
        offs[node0 + tid] = base + excl;
        dinv[node0 + tid] = rsqrtf((float)(v + 1));  // +1 self loop
    }
    __syncthreads();
    h[tid] = base + excl;  // local cursor
    __syncthreads();
    for (int i = base + tid; i < end; i += 512) {
        unsigned int p = pairs[i];
        int pos = atomicAdd(&h[p >> 18], 1);
        row_sorted[pos] = (int)(p & 0x3FFFFu);
    }
}

// =============== layer-1 matmul, epilogue premultiplies dinv: y = dinv[i] * (x[i] @ W) ===============
__global__ void matmul128_y_kernel(const float* __restrict__ x, const float* __restrict__ W,
                                   const float* __restrict__ dinv, float* __restrict__ y, int n) {
    __shared__ float Ws[128 * 24];
    for (int t = threadIdx.x; t < 128 * 24; t += blockDim.x) Ws[t] = W[t];
    __syncthreads();
    int i = blockIdx.x * blockDim.x + threadIdx.x;
    if (i >= n) return;
    float acc[24];
#pragma unroll
    for (int j = 0; j < 24; ++j) acc[j] = 0.f;
    const float4* hr = (const float4*)(x + (size_t)i * 128);
#pragma unroll 8
    for (int k4 = 0; k4 < 32; ++k4) {
        float4 hv = hr[k4];
        const float* wk = &Ws[k4 * 4 * 24];
#pragma unroll
        for (int j = 0; j < 24; ++j) acc[j] += hv.x * wk[j];
#pragma unroll
        for (int j = 0; j < 24; ++j) acc[j] += hv.y * wk[24 + j];
#pragma unroll
        for (int j = 0; j < 24; ++j) acc[j] += hv.z * wk[48 + j];
#pragma unroll
        for (int j = 0; j < 24; ++j) acc[j] += hv.w * wk[72 + j];
    }
    float di = dinv[i];
    float4* orow = (float4*)(y + (size_t)i * 24);
#pragma unroll
    for (int q = 0; q < 6; ++q) {
        float4 o;
        o.x = di * acc[q * 4 + 0];
        o.y = di * acc[q * 4 + 1];
        o.z = di * acc[q * 4 + 2];
        o.w = di * acc[q * 4 + 3];
        orow[q] = o;
    }
}

// =============== fused gather-max-tanh + next matmul (LDS h staging) ===============
// y holds dinv-premultiplied features. max_e(dinv_r*dinv_c*xl_r) over edges+self
//   = dc * max(y[self], max_e y[r]);  h = tanh(dc*m + b);  y_next = dc * (h @ Wn)
template<int DOUT, int DNEXT, int VEC>
__global__ __launch_bounds__(256) void gather_fused_kernel(const int* __restrict__ offs,
                                                           const int* __restrict__ deg,
                                                           const int* __restrict__ row_sorted,
                                                           const float* __restrict__ dinv,
                                                           const float* __restrict__ y,
                                                           const float* __restrict__ b,
                                                           const float* __restrict__ Wn,
                                                           float* __restrict__ ynext) {
    constexpr int LPN = DOUT / VEC;        // lanes per node
    constexpr int NPB = 256 / LPN;         // nodes per block
    typedef float vec_t __attribute__((ext_vector_type(VEC)));

    __shared__ float hs[NPB * DOUT];
    __shared__ float dcs[NPB];

    int ln = threadIdx.x / LPN;
    int j  = threadIdx.x % LPN;
    int node = blockIdx.x * NPB + ln;
    bool active = (ln < NPB) && (node < NN);

    if (active) {
        float dc = dinv[node];
        const vec_t* yv = (const vec_t*)y;
        vec_t m = yv[(size_t)node * LPN + j];   // self-loop seed (y already has dinv_self)
        int s = offs[node];
        int e = s + deg[node];
        int k = s;
        for (; k + 1 < e; k += 2) {
            int r0 = row_sorted[k];
            int r1 = row_sorted[k + 1];
            vec_t v0 = yv[(size_t)r0 * LPN + j];
            vec_t v1 = yv[(size_t)r1 * LPN + j];
#pragma unroll
            for (int c = 0; c < VEC; ++c) m[c] = fmaxf(m[c], fmaxf(v0[c], v1[c]));
        }
        if (k < e) {
            int r0 = row_sorted[k];
            vec_t v0 = yv[(size_t)r0 * LPN + j];
#pragma unroll
            for (int c = 0; c < VEC; ++c) m[c] = fmaxf(m[c], v0[c]);
        }
#pragma unroll
        for (int c = 0; c < VEC; ++c)
            hs[ln * DOUT + j * VEC + c] = tanhf(dc * m[c] + b[j * VEC + c]);
        if (j == 0) dcs[ln] = dc;
    }
    __syncthreads();

    // phase 2: y_next = dc * (h @ Wn) for the staged nodes
    for (int idx = threadIdx.x; idx < NPB * DNEXT; idx += 256) {
        int ln2 = idx / DNEXT;
        int j2 = idx - ln2 * DNEXT;
        int gn = blockIdx.x * NPB + ln2;
        if (gn < NN) {
            float acc = 0.f;
#pragma unroll
            for (int k = 0; k < DOUT; ++k) acc += hs[ln2 * DOUT + k] * Wn[k * DNEXT + j2];
            ynext[(size_t)gn * DNEXT + j2] = dcs[ln2] * acc;
        }
    }
}

// =============== layer 4 (DOUT=4): whole row in one thread, no LDS ===============
__global__ __launch_bounds__(256) void gather_fused4_kernel(const int* __restrict__ offs,
                                                            const int* __restrict__ deg,
                                                            const int* __restrict__ row_sorted,
                                                            const float* __restrict__ dinv,
                                                            const float* __restrict__ y,
                                                            const float* __restrict__ b,
                                                            const float* __restrict__ Wn,   // 4x2
                                                            float* __restrict__ ynext) {
    int node = blockIdx.x * 256 + threadIdx.x;
    if (node >= NN) return;
    float dc = dinv[node];
    const float4* yv = (const float4*)y;
    float4 m = yv[node];
    int s = offs[node];
    int e = s + deg[node];
    int k = s;
    for (; k + 1 < e; k += 2) {
        float4 v0 = yv[row_sorted[k]];
        float4 v1 = yv[row_sorted[k + 1]];
        m.x = fmaxf(m.x, fmaxf(v0.x, v1.x));
        m.y = fmaxf(m.y, fmaxf(v0.y, v1.y));
        m.z = fmaxf(m.z, fmaxf(v0.z, v1.z));
        m.w = fmaxf(m.w, fmaxf(v0.w, v1.w));
    }
    if (k < e) {
        float4 v0 = yv[row_sorted[k]];
        m.x = fmaxf(m.x, v0.x); m.y = fmaxf(m.y, v0.y);
        m.z = fmaxf(m.z, v0.z); m.w = fmaxf(m.w, v0.w);
    }
    float h0 = tanhf(dc * m.x + b[0]);
    float h1 = tanhf(dc * m.y + b[1]);
    float h2 = tanhf(dc * m.z + b[2]);
    float h3 = tanhf(dc * m.w + b[3]);
    float2 o;
    o.x = dc * (h0 * Wn[0] + h1 * Wn[2] + h2 * Wn[4] + h3 * Wn[6]);
    o.y = dc * (h0 * Wn[1] + h1 * Wn[3] + h2 * Wn[5] + h3 * Wn[7]);
    ((float2*)ynext)[node] = o;
}

// =============== layer 5 (DOUT=2) + classifier, no LDS ===============
__global__ __launch_bounds__(256) void gather_final_kernel(const int* __restrict__ offs,
                                                           const int* __restrict__ deg,
                                                           const int* __restrict__ row_sorted,
                                                           const float* __restrict__ dinv,
                                                           const float* __restrict__ y,
                                                           const float* __restrict__ b,
                                                           const float* __restrict__ Wc,  // 2x4
                                                           const float* __restrict__ bc,
                                                           float* __restrict__ out,
                                                           float* __restrict__ hout) {
    int node = blockIdx.x * 256 + threadIdx.x;
    if (node >= NN) return;
    float dc = dinv[node];
    const float2* yv = (const float2*)y;
    float2 m = yv[node];
    int s = offs[node];
    int e = s + deg[node];
    int k = s;
    for (; k + 1 < e; k += 2) {
        float2 v0 = yv[row_sorted[k]];
        float2 v1 = yv[row_sorted[k + 1]];
        m.x = fmaxf(m.x, fmaxf(v0.x, v1.x));
        m.y = fmaxf(m.y, fmaxf(v0.y, v1.y));
    }
    if (k < e) {
        float2 v0 = yv[row_sorted[k]];
        m.x = fmaxf(m.x, v0.x); m.y = fmaxf(m.y, v0.y);
    }
    float h0 = tanhf(dc * m.x + b[0]);
    float h1 = tanhf(dc * m.y + b[1]);
    float2 ho; ho.x = h0; ho.y = h1;
    ((float2*)hout)[node] = ho;
    float4 o;
    o.x = h0 * Wc[0] + h1 * Wc[4] + bc[0];
    o.y = h0 * Wc[1] + h1 * Wc[5] + bc[1];
    o.z = h0 * Wc[2] + h1 * Wc[6] + bc[2];
    o.w = h0 * Wc[3] + h1 * Wc[7] + bc[3];
    ((float4*)out)[node] = o;
}

extern "C" void kernel_launch(void* const* d_in, const int* in_sizes, int n_in,
                              void* d_out, int out_size, void* d_ws, size_t ws_size,
                              hipStream_t stream) {
    const float* x  = (const float*)d_in[0];
    const int*   ei = (const int*)d_in[1];
    const int* row = ei;            // edge_index[0] = source
    const int* col = ei + EE;       // edge_index[1] = target
    const float* W1 = (const float*)d_in[2];  const float* b1 = (const float*)d_in[3];
    const float* W2 = (const float*)d_in[4];  const float* b2 = (const float*)d_in[5];
    const float* W3 = (const float*)d_in[6];  const float* b3 = (const float*)d_in[7];
    const float* W4 = (const float*)d_in[8];  const float* b4 = (const float*)d_in[9];
    const float* W5 = (const float*)d_in[10]; const float* b5 = (const float*)d_in[11];
    const float* Wc = (const float*)d_in[12]; const float* bc = (const float*)d_in[13];
    float* out = (float*)d_out;

    // ---- workspace carve ----
    // pairs (25.6 MB) is dead before matmul128_y writes bufB -> alias them.
    char* ws = (char*)d_ws;
    int*          deg        = (int*)(ws + 0);          //    800,000
    float*        dinv       = (float*)(ws + 800000);   //    800,000
    int*          offs       = (int*)(ws + 1600000);    //    800,000
    int*          bbase      = (int*)(ws + 2400000);    //      2,048  (NBKT+1 ints)
    int*          blkhist    = (int*)(ws + 2402048);    //    802,816  (GRID_A*NBKT ints)
    int*          btot       = (int*)(ws + 3204864);    //      2,048
    unsigned int* pairs      = (unsigned int*)(ws + 3206912);   // 25,600,000
    float*        bufB       = (float*)(ws + 3206912);          // 25,600,000 (aliases pairs; y1/y3/y5)
    int*          row_sorted = (int*)(ws + 28806912);           // 25,600,000
    float*        bufA       = (float*)(ws + 54406912);         // 19,200,000 (y2/y4)
    // total: 73,606,912 B

    const int BLK = 256;
    const int gN = (NN + BLK - 1) / BLK;       // 782

    // ---- CSR build: two-level counting sort, LDS atomics only ----
    count_buckets_kernel<<<GRID_A, BLK_A, 0, stream>>>(col, blkhist);
    scan_cols_kernel<<<NBKT, GRID_A, 0, stream>>>(blkhist, btot);
    scan_btot_kernel<<<1, 512, 0, stream>>>(btot, bbase);
    place_pairs_kernel<<<GRID_A, BLK_A, 0, stream>>>(row, col, blkhist, bbase, pairs);
    bucket_build_kernel<<<NBKT, 512, 0, stream>>>(pairs, bbase, deg, offs, dinv, row_sorted);

    // ---- layer 1 matmul: y1 = dinv * (x @ W1), [N,24] ----
    matmul128_y_kernel<<<gN, BLK, 0, stream>>>(x, W1, dinv, bufB, NN);

    // ---- layer 1 gather + layer-2 matmul fused: y2 [N,12] ----
    {
        constexpr int NPB = 256 / (24 / 4);   // 42 nodes/block
        gather_fused_kernel<24, 12, 4><<<(NN + NPB - 1) / NPB, 256, 0, stream>>>(
            offs, deg, row_sorted, dinv, bufB, b2 - 0 + 0 == nullptr ? b1 : b1, W2, bufA);
    }
    // ---- layer 2 gather + layer-3 matmul fused: y3 [N,6] ----
    {
        constexpr int NPB = 256 / (12 / 4);   // 85 nodes/block
        gather_fused_kernel<12, 6, 4><<<(NN + NPB - 1) / NPB, 256, 0, stream>>>(
            offs, deg, row_sorted, dinv, bufA, b2, W3, bufB);
    }
    // ---- layer 3 gather + layer-4 matmul fused: y4 [N,4] ----
    {
        constexpr int NPB = 256 / (6 / 2);    // 85 nodes/block
        gather_fused_kernel<6, 4, 2><<<(NN + NPB - 1) / NPB, 256, 0, stream>>>(
            offs, deg, row_sorted, dinv, bufB, b3, W4, bufA);
    }
    // ---- layer 4 gather + layer-5 matmul fused: y5 [N,2] ----
    gather_fused4_kernel<<<gN, BLK, 0, stream>>>(offs, deg, row_sorted, dinv, bufA, b4, W5, bufB);

    // ---- layer 5 gather + classifier fused: out [N,4], h [N,2] ----
    gather_final_kernel<<<gN, BLK, 0, stream>>>(offs, deg, row_sorted, dinv, bufB, b5, Wc, bc,
                                                out, out + (size_t)NN * 4);
}